// Round 7
// baseline (280.328 us; speedup 1.0000x reference)
//
#include <hip/hip_runtime.h>
#include <limits.h>
#include <math.h>

#define GRID 64
#define NUM_VOXELS (GRID * GRID * GRID)   // 262144
#define KSLOTS 16
#define CAP 32                            // per-voxel scratch capacity
#define FEAT 29

typedef float f32x4 __attribute__((ext_vector_type(4)));  // NT builtins need a
                                                          // clang vector, not
                                                          // HIP_vector_type

// Pass 1: scatter packed (conf,pid) keys into per-voxel lists.
// Key = (conf_bits << 32) | ~pid. conf >= 0 so conf_bits is monotonic in
// value; MAX key == (conf desc, pid asc) — the reference's stable double-sort
// order, deterministic regardless of atomic arrival order.
// Binning math: XLA folds (p - MIN)/0.02 -> (p - MIN) * 50.0f exactly; we
// must use the multiply (NOT an IEEE divide) to match floor() at boundaries.
__global__ __launch_bounds__(256) void scatter_kernel(
    const float* __restrict__ pts, const float* __restrict__ conf, int n,
    int* __restrict__ cnt, unsigned long long* __restrict__ buf) {
    int i = blockIdx.x * blockDim.x + threadIdx.x;
    if (i >= n) return;
    const float minc = (float)(-(64.0 * 0.02) / 2.0);  // -0.63999998569488525f
    const float rinv = 50.0f;                          // fold(1/0.02f) == 50.0f
    float x = pts[(size_t)i * 3 + 0];
    float y = pts[(size_t)i * 3 + 1];
    float z = pts[(size_t)i * 3 + 2];
    int ix = (int)floorf((x - minc) * rinv);
    int iy = (int)floorf((y - minc) * rinv);
    int iz = (int)floorf((z - minc) * rinv);
    if ((unsigned)ix >= GRID || (unsigned)iy >= GRID || (unsigned)iz >= GRID) return;
    int v = ix * (GRID * GRID) + iy * GRID + iz;
    int pos = atomicAdd(&cnt[v], 1);
    if (pos < CAP) {
        unsigned int cb = __float_as_uint(conf[i]);
        unsigned long long key =
            ((unsigned long long)cb << 32) | (unsigned int)(~i);
        buf[(size_t)v * CAP + pos] = key;
    }
}

// Fused select+gather: one block = 16 voxels x 16 slots.
//  Phase A: lanes 0..15 each run the top-16 insertion select for one voxel
//           (unrolled 16-deep u64 compare-swap; empty sentinel 0), stash
//           pids in LDS.
//  Phase B: all 256 threads: write out_idx (coalesced, NT), vector-load the
//           29-float feature row (desc via 6x NT 16B loads), stage in LDS,
//           stream the contiguous 29696B block out as NT 16B stores.
// Scratch (cnt/buf) lives in d_ws, so phase-B writes never race phase-A reads.
__global__ __launch_bounds__(256) void select_gather_kernel(
    const float* __restrict__ pts, const float* __restrict__ conf,
    const float* __restrict__ desc, const float* __restrict__ desc_conf,
    const int* __restrict__ cnt, const unsigned long long* __restrict__ buf,
    float* __restrict__ out_idx, float* __restrict__ out_feat) {
    const int tid = threadIdx.x;
    const int vbase = blockIdx.x * 16;

    __shared__ int spid[256];
    __shared__ __align__(16) float st[256 * FEAT];   // 29696 B

    if (tid < 16) {
        int v = vbase + tid;
        unsigned long long top[KSLOTS];
        #pragma unroll
        for (int s = 0; s < KSLOTS; ++s) top[s] = 0ULL;
        int n = cnt[v];
        if (n > CAP) n = CAP;
        const unsigned long long* row = buf + (size_t)v * CAP;
        for (int j = 0; j < n; ++j) {
            unsigned long long key = row[j];
            #pragma unroll
            for (int s = 0; s < KSLOTS; ++s) {
                unsigned long long hi = key > top[s] ? key : top[s];
                unsigned long long lo = key > top[s] ? top[s] : key;
                top[s] = hi;
                key    = lo;
            }
        }
        #pragma unroll
        for (int s = 0; s < KSLOTS; ++s) {
            unsigned long long k = top[s];
            spid[tid * 16 + s] = (k != 0ULL) ? (int)(~(unsigned int)k) : -1;
        }
    }
    __syncthreads();

    // out_idx layout: (v,s) flat == vbase*16 + tid. Exact float for ids < 2^24.
    int pid = spid[tid];
    __builtin_nontemporal_store((float)pid, &out_idx[(size_t)vbase * KSLOTS + tid]);

    float f[FEAT];
    #pragma unroll
    for (int e = 0; e < FEAT; ++e) f[e] = 0.0f;
    if (pid >= 0) {
        f[0] = pts[(size_t)pid * 3 + 0];
        f[1] = pts[(size_t)pid * 3 + 1];
        f[2] = pts[(size_t)pid * 3 + 2];
        f[3] = conf[pid];
        const f32x4* d4 = (const f32x4*)(desc) + (size_t)pid * 6;  // 96B rows
        #pragma unroll
        for (int q = 0; q < 6; ++q) {
            f32x4 d = __builtin_nontemporal_load(&d4[q]);  // no reuse: skip caches
            f[4 + q * 4 + 0] = d.x;
            f[4 + q * 4 + 1] = d.y;
            f[4 + q * 4 + 2] = d.z;
            f[4 + q * 4 + 3] = d.w;
        }
        f[28] = desc_conf[pid];
    }
    #pragma unroll
    for (int e = 0; e < FEAT; ++e) st[tid * FEAT + e] = f[e];
    __syncthreads();

    // 256*29 floats = 1856 16B-vectors, contiguous, 16B-aligned.
    f32x4* dst = (f32x4*)(out_feat + (size_t)vbase * KSLOTS * FEAT);
    const f32x4* src = (const f32x4*)st;
    #pragma unroll
    for (int k = tid; k < 256 * FEAT / 4; k += 256)
        __builtin_nontemporal_store(src[k], &dst[k]);
}

// ---- Fallback path (only if d_ws is too small): round-5 proven kernels ----
__global__ __launch_bounds__(256) void select_kernel(
    const int* __restrict__ cnt, const unsigned long long* __restrict__ buf,
    float* __restrict__ out_idx) {
    int v = blockIdx.x * blockDim.x + threadIdx.x;
    if (v >= NUM_VOXELS) return;
    unsigned long long top[KSLOTS];
    #pragma unroll
    for (int s = 0; s < KSLOTS; ++s) top[s] = 0ULL;
    int n = cnt[v];
    if (n > CAP) n = CAP;
    const unsigned long long* row = buf + (size_t)v * CAP;
    for (int j = 0; j < n; ++j) {
        unsigned long long key = row[j];
        #pragma unroll
        for (int s = 0; s < KSLOTS; ++s) {
            unsigned long long hi = key > top[s] ? key : top[s];
            unsigned long long lo = key > top[s] ? top[s] : key;
            top[s] = hi;
            key    = lo;
        }
    }
    float* o = out_idx + (size_t)v * KSLOTS;
    #pragma unroll
    for (int s = 0; s < KSLOTS; ++s) {
        unsigned long long k = top[s];
        o[s] = (float)((k != 0ULL) ? (int)(~(unsigned int)k) : -1);
    }
}

__global__ __launch_bounds__(256) void gather_kernel(
    const float* __restrict__ pts, const float* __restrict__ conf,
    const float* __restrict__ desc, const float* __restrict__ desc_conf,
    const float* __restrict__ out_idx, float* __restrict__ out_feat) {
    const int t = threadIdx.x;
    const size_t slot0 = (size_t)blockIdx.x * 256;
    const size_t slot  = slot0 + t;
    __shared__ __align__(16) float st[256 * FEAT];
    int pid = (int)out_idx[slot];
    float f[FEAT];
    #pragma unroll
    for (int e = 0; e < FEAT; ++e) f[e] = 0.0f;
    if (pid >= 0) {
        f[0] = pts[(size_t)pid * 3 + 0];
        f[1] = pts[(size_t)pid * 3 + 1];
        f[2] = pts[(size_t)pid * 3 + 2];
        f[3] = conf[pid];
        const f32x4* d4 = (const f32x4*)(desc) + (size_t)pid * 6;
        #pragma unroll
        for (int q = 0; q < 6; ++q) {
            f32x4 d = d4[q];
            f[4 + q * 4 + 0] = d.x; f[4 + q * 4 + 1] = d.y;
            f[4 + q * 4 + 2] = d.z; f[4 + q * 4 + 3] = d.w;
        }
        f[28] = desc_conf[pid];
    }
    #pragma unroll
    for (int e = 0; e < FEAT; ++e) st[t * FEAT + e] = f[e];
    __syncthreads();
    f32x4* dst = (f32x4*)(out_feat + slot0 * FEAT);
    const f32x4* src = (const f32x4*)st;
    #pragma unroll
    for (int k = t; k < 256 * FEAT / 4; k += 256) dst[k] = src[k];
}

extern "C" void kernel_launch(void* const* d_in, const int* in_sizes, int n_in,
                              void* d_out, int out_size, void* d_ws, size_t ws_size,
                              hipStream_t stream) {
    const float* pts       = (const float*)d_in[0];
    const float* conf      = (const float*)d_in[1];
    const float* desc      = (const float*)d_in[2];
    const float* desc_conf = (const float*)d_in[3];
    const int n = in_sizes[1];  // conf is (N,)

    float* out_idx  = (float*)d_out;                         // (V,16) as float
    float* out_feat = out_idx + (size_t)NUM_VOXELS * KSLOTS; // (V,16,29)

    const size_t need = (size_t)NUM_VOXELS * 4              // cnt
                      + (size_t)NUM_VOXELS * CAP * 8;       // buf (65 MB)

    if (ws_size >= need) {
        // Scratch in d_ws: fused path (no race between phase B writes and
        // other blocks' phase A reads).
        int* cnt = (int*)d_ws;
        unsigned long long* buf = (unsigned long long*)((char*)d_ws + (size_t)NUM_VOXELS * 4);
        (void)hipMemsetAsync(cnt, 0, NUM_VOXELS * sizeof(int), stream);
        scatter_kernel<<<(n + 255) / 256, 256, 0, stream>>>(pts, conf, n, cnt, buf);
        select_gather_kernel<<<NUM_VOXELS / 16, 256, 0, stream>>>(
            pts, conf, desc, desc_conf, cnt, buf, out_idx, out_feat);
    } else {
        // Fallback: scratch at the head of the X region, separate select+gather.
        int* cnt = (int*)out_feat;
        unsigned long long* buf = (unsigned long long*)(out_feat + NUM_VOXELS);
        (void)hipMemsetAsync(cnt, 0, NUM_VOXELS * sizeof(int), stream);
        scatter_kernel<<<(n + 255) / 256, 256, 0, stream>>>(pts, conf, n, cnt, buf);
        select_kernel<<<NUM_VOXELS / 256, 256, 0, stream>>>(cnt, buf, out_idx);
        gather_kernel<<<(NUM_VOXELS * KSLOTS) / 256, 256, 0, stream>>>(
            pts, conf, desc, desc_conf, out_idx, out_feat);
    }
}

// Round 8
// 239.283 us; speedup vs baseline: 1.1715x; 1.1715x over previous
//
#include <hip/hip_runtime.h>
#include <limits.h>
#include <math.h>

#define GRID 64
#define NUM_VOXELS (GRID * GRID * GRID)   // 262144
#define KSLOTS 16
#define CAP 32                            // per-voxel scratch capacity
#define FEAT 29

typedef float f32x4 __attribute__((ext_vector_type(4)));  // NT builtins need a
                                                          // clang vector type

// Pass 1: scatter packed (conf,pid) keys into per-voxel lists.
// Key = (conf_bits << 32) | ~pid. conf >= 0 so conf_bits is monotonic in
// value; MAX key == (conf desc, pid asc) — the reference's stable double-sort
// order, deterministic regardless of atomic arrival order.
// Binning math: XLA folds (p - MIN)/0.02 -> (p - MIN) * 50.0f exactly; we
// must use the multiply (NOT an IEEE divide) to match floor() at boundaries.
__global__ __launch_bounds__(256) void scatter_kernel(
    const float* __restrict__ pts, const float* __restrict__ conf, int n,
    int* __restrict__ cnt, unsigned long long* __restrict__ buf) {
    int i = blockIdx.x * blockDim.x + threadIdx.x;
    if (i >= n) return;
    const float minc = (float)(-(64.0 * 0.02) / 2.0);  // -0.63999998569488525f
    const float rinv = 50.0f;                          // fold(1/0.02f) == 50.0f
    float x = pts[(size_t)i * 3 + 0];
    float y = pts[(size_t)i * 3 + 1];
    float z = pts[(size_t)i * 3 + 2];
    int ix = (int)floorf((x - minc) * rinv);
    int iy = (int)floorf((y - minc) * rinv);
    int iz = (int)floorf((z - minc) * rinv);
    if ((unsigned)ix >= GRID || (unsigned)iy >= GRID || (unsigned)iz >= GRID) return;
    int v = ix * (GRID * GRID) + iy * GRID + iz;
    int pos = atomicAdd(&cnt[v], 1);
    if (pos < CAP) {
        unsigned int cb = __float_as_uint(conf[i]);
        unsigned long long key =
            ((unsigned long long)cb << 32) | (unsigned int)(~i);
        buf[(size_t)v * CAP + pos] = key;
    }
}

// Pass 2: one THREAD per voxel. Top-16 by key via unrolled 16-deep
// compare-swap insertion (static indices -> registers). Empty sentinel 0.
__global__ __launch_bounds__(256) void select_kernel(
    const int* __restrict__ cnt, const unsigned long long* __restrict__ buf,
    float* __restrict__ out_idx) {
    int v = blockIdx.x * blockDim.x + threadIdx.x;
    if (v >= NUM_VOXELS) return;
    unsigned long long top[KSLOTS];
    #pragma unroll
    for (int s = 0; s < KSLOTS; ++s) top[s] = 0ULL;
    int n = cnt[v];
    if (n > CAP) n = CAP;
    const unsigned long long* row = buf + (size_t)v * CAP;
    for (int j = 0; j < n; ++j) {
        unsigned long long key = row[j];
        #pragma unroll
        for (int s = 0; s < KSLOTS; ++s) {
            unsigned long long hi = key > top[s] ? key : top[s];
            unsigned long long lo = key > top[s] ? top[s] : key;
            top[s] = hi;
            key    = lo;
        }
    }
    float* o = out_idx + (size_t)v * KSLOTS;
    #pragma unroll
    for (int s = 0; s < KSLOTS; ++s) {
        unsigned long long k = top[s];
        o[s] = (float)((k != 0ULL) ? (int)(~(unsigned int)k) : -1);
    }
}

// Pass 3: feature gather, thread-per-slot. Cached vector loads (desc via
// 6x float4), LDS staging, NT streaming stores for the 479MB output (no
// reader -> keep L2/L3 for the gather working set).
__global__ __launch_bounds__(256) void gather_kernel(
    const float* __restrict__ pts, const float* __restrict__ conf,
    const float* __restrict__ desc, const float* __restrict__ desc_conf,
    const float* __restrict__ out_idx, float* __restrict__ out_feat) {
    const int t = threadIdx.x;
    const size_t slot0 = (size_t)blockIdx.x * 256;
    const size_t slot  = slot0 + t;
    __shared__ __align__(16) float st[256 * FEAT];   // 29696 B
    int pid = (int)out_idx[slot];
    float f[FEAT];
    #pragma unroll
    for (int e = 0; e < FEAT; ++e) f[e] = 0.0f;
    if (pid >= 0) {
        f[0] = pts[(size_t)pid * 3 + 0];
        f[1] = pts[(size_t)pid * 3 + 1];
        f[2] = pts[(size_t)pid * 3 + 2];
        f[3] = conf[pid];
        const f32x4* d4 = (const f32x4*)(desc) + (size_t)pid * 6;  // 96B rows
        #pragma unroll
        for (int q = 0; q < 6; ++q) {
            f32x4 d = d4[q];
            f[4 + q * 4 + 0] = d.x; f[4 + q * 4 + 1] = d.y;
            f[4 + q * 4 + 2] = d.z; f[4 + q * 4 + 3] = d.w;
        }
        f[28] = desc_conf[pid];
    }
    #pragma unroll
    for (int e = 0; e < FEAT; ++e) st[t * FEAT + e] = f[e];
    __syncthreads();
    // 256*29 floats = 1856 16B-vectors, contiguous, 16B-aligned.
    f32x4* dst = (f32x4*)(out_feat + slot0 * FEAT);
    const f32x4* src = (const f32x4*)st;
    #pragma unroll
    for (int k = t; k < 256 * FEAT / 4; k += 256)
        __builtin_nontemporal_store(src[k], &dst[k]);
}

extern "C" void kernel_launch(void* const* d_in, const int* in_sizes, int n_in,
                              void* d_out, int out_size, void* d_ws, size_t ws_size,
                              hipStream_t stream) {
    const float* pts       = (const float*)d_in[0];
    const float* conf      = (const float*)d_in[1];
    const float* desc      = (const float*)d_in[2];
    const float* desc_conf = (const float*)d_in[3];
    const int n = in_sizes[1];  // conf is (N,)

    float* out_idx  = (float*)d_out;                         // (V,16) as float
    float* out_feat = out_idx + (size_t)NUM_VOXELS * KSLOTS; // (V,16,29)

    const size_t need = (size_t)NUM_VOXELS * 4              // cnt (1 MB)
                      + (size_t)NUM_VOXELS * CAP * 8;       // buf (64 MB)

    int* cnt;
    unsigned long long* buf;
    if (ws_size >= need) {
        cnt = (int*)d_ws;
        buf = (unsigned long long*)((char*)d_ws + (size_t)NUM_VOXELS * 4);
    } else {
        // Fallback: scratch at the head of the X region (gather rewrites it
        // deterministically afterwards).
        cnt = (int*)out_feat;
        buf = (unsigned long long*)(out_feat + NUM_VOXELS);
    }

    (void)hipMemsetAsync(cnt, 0, NUM_VOXELS * sizeof(int), stream);
    scatter_kernel<<<(n + 255) / 256, 256, 0, stream>>>(pts, conf, n, cnt, buf);
    select_kernel<<<NUM_VOXELS / 256, 256, 0, stream>>>(cnt, buf, out_idx);
    gather_kernel<<<(NUM_VOXELS * KSLOTS) / 256, 256, 0, stream>>>(
        pts, conf, desc, desc_conf, out_idx, out_feat);
}